// Round 14
// baseline (1734.707 us; speedup 1.0000x reference)
//
#include <hip/hip_runtime.h>
#include <hip/hip_bf16.h>
#include <stdint.h>

#define N_NODESC 50000
#define NPAD     50048   // 391 * 128
#define NPAD2    50176   // 392 * 128 (8 XCD bands x 49 row-tiles)
#define N_EDGESC 800000
#define DIM      256
#define DIM3     768
#define NSTEPS   5
#define NGRAPH   64

typedef __attribute__((ext_vector_type(4))) float  f32x4;
typedef __attribute__((ext_vector_type(8))) short  short8;
typedef __attribute__((ext_vector_type(4))) unsigned short u16x4;

// ---------------- device-global scratch (no d_ws dependence) ----------------
__device__ float          g_hf[(size_t)NPAD2 * DIM];
__device__ unsigned short g_ah[(size_t)NPAD2 * 768];     // [a(256) | hA(256) | hB(256)]
__device__ unsigned short g_p [(size_t)NPAD2 * DIM3];
__device__ unsigned short g_Wc[DIM * DIM3];
__device__ unsigned short g_WC3[1024 * 512];             // piece-permuted gate weights
__device__ int            g_cnt[NPAD2 * 4];
__device__ int            g_rowoff[N_NODESC + 1];
__device__ int            g_cur[N_NODESC];
__device__ unsigned       g_eidx[N_EDGESC];
__device__ int            g_bsum[256];
__device__ int            g_boff[256];
__device__ float          g_gate[N_NODESC];
__device__ int            g_soff[NGRAPH + 1];
__device__ float          g_gmax[NGRAPH];
__device__ float          g_gden[NGRAPH];

__device__ __forceinline__ float bf2f(unsigned short u) {
  unsigned x = ((unsigned)u) << 16;
  return __builtin_bit_cast(float, x);
}
__device__ __forceinline__ unsigned short f2bf(float f) {
  unsigned u = __builtin_bit_cast(unsigned, f);
  u += 0x7fffu + ((u >> 16) & 1u);
  return (unsigned short)(u >> 16);
}
__device__ __forceinline__ float sigm(float x) { return 1.0f / (1.0f + expf(-x)); }

__device__ __forceinline__ void async16(const void* g, void* l) {
  __builtin_amdgcn_global_load_lds(
      (const __attribute__((address_space(1))) unsigned int*)g,
      (__attribute__((address_space(3))) unsigned int*)l, 16, 0, 0);
}

// ---------------- once-per-launch prep ----------------

__global__ void k_zero_cnt() {
  int i = blockIdx.x * 256 + threadIdx.x;   // NPAD2*4 = 200704 = 784*256
  g_cnt[i] = 0;
}

// Wc[f][e*256+d] = W_msg[e][d][f].
// WC3: for dim-group g (dims D_g=[g*64,g*64+64)), rows [g*256, g*256+256) =
//   [64 r-rows | 64 z-rows | 64 i_n-rows | 64 h_n-rows] for d in D_g, each row
//   512 wide = [wih-half(256) | whh-half(256)] (i_n: whh-half zero; h_n: wih-half zero).
__global__ void k_prep_w(const float* __restrict__ Wmsg, const float* __restrict__ wih,
                         const float* __restrict__ whh) {
  int i = blockIdx.x * 256 + threadIdx.x;   // 720896 = 2816*256
  if (i < 196608) {
    int f = i / 768, j = i - f * 768;      // j = e*256 + d
    int e = j >> 8, d = j & 255;
    g_Wc[i] = f2bf(Wmsg[(e << 16) + (d << 8) + f]);
  } else if (i < 720896) {
    int t = i - 196608;
    int c3 = t >> 9, k = t & 511;
    int g = c3 >> 8, rem = c3 & 255, p = rem >> 6, d = g * 64 + (rem & 63);
    float v;
    if (p == 0) { int rw = d;       v = (k < 256) ? wih[rw * 256 + k] : whh[rw * 256 + k - 256]; }
    else if (p == 1) { int rw = 256 + d; v = (k < 256) ? wih[rw * 256 + k] : whh[rw * 256 + k - 256]; }
    else if (p == 2) { int rw = 512 + d; v = (k < 256) ? wih[rw * 256 + k] : 0.f; }
    else { int rw = 512 + d; v = (k < 256) ? 0.f : whh[rw * 256 + k - 256]; }
    g_WC3[t] = f2bf(v);
  }
}

__global__ void k_embed(const int* __restrict__ x, const float* __restrict__ emb) {
  int i = blockIdx.x * 256 + threadIdx.x;        // N_NODESC*64 total
  int n = i >> 6, t = i & 63;
  if (n >= N_NODESC) return;
  float4 v = *(const float4*)(emb + (size_t)x[n] * DIM + t * 4);
  *(float4*)(g_hf + (size_t)n * DIM + t * 4) = v;
  u16x4 b = {f2bf(v.x), f2bf(v.y), f2bf(v.z), f2bf(v.w)};
  *(u16x4*)(g_ah + (size_t)n * 768 + 256 + t * 4) = b;   // hA
}

__global__ void k_count(const int* __restrict__ dst, const int* __restrict__ et) {
  int e = blockIdx.x * 256 + threadIdx.x;
  if (e >= N_EDGESC) return;
  atomicAdd(&g_cnt[dst[e] * 4 + et[e]], 1);
}

__global__ void k_scan1() {
  __shared__ int lds[256];
  int n = blockIdx.x * 256 + threadIdx.x;
  int deg = (n < N_NODESC) ? (g_cnt[n * 4] + g_cnt[n * 4 + 1] + g_cnt[n * 4 + 2]) : 0;
  lds[threadIdx.x] = deg;
  __syncthreads();
  for (int o = 128; o > 0; o >>= 1) {
    if (threadIdx.x < o) lds[threadIdx.x] += lds[threadIdx.x + o];
    __syncthreads();
  }
  if (threadIdx.x == 0) g_bsum[blockIdx.x] = lds[0];
}

__global__ void k_scan2() {
  __shared__ int lds[256];
  int t = threadIdx.x;
  int v = (t < 196) ? g_bsum[t] : 0;
  lds[t] = v;
  __syncthreads();
  for (int o = 1; o < 256; o <<= 1) {
    int u = (t >= o) ? lds[t - o] : 0;
    __syncthreads();
    lds[t] += u;
    __syncthreads();
  }
  if (t < 196) g_boff[t] = lds[t] - v;   // exclusive
}

__global__ void k_scan3() {
  __shared__ int lds[256];
  int n = blockIdx.x * 256 + threadIdx.x;
  int t = threadIdx.x;
  int deg = (n < N_NODESC) ? (g_cnt[n * 4] + g_cnt[n * 4 + 1] + g_cnt[n * 4 + 2]) : 0;
  lds[t] = deg;
  __syncthreads();
  for (int o = 1; o < 256; o <<= 1) {
    int u = (t >= o) ? lds[t - o] : 0;
    __syncthreads();
    lds[t] += u;
    __syncthreads();
  }
  if (n < N_NODESC) {
    int off = g_boff[blockIdx.x] + lds[t] - deg;
    g_rowoff[n] = off;
    g_cur[n] = off;
  }
  if (n == N_NODESC - 1) g_rowoff[N_NODESC] = g_boff[blockIdx.x] + lds[t];
}

__global__ void k_fill(const int* __restrict__ src, const int* __restrict__ dst,
                       const int* __restrict__ et) {
  int e = blockIdx.x * 256 + threadIdx.x;
  if (e >= N_EDGESC) return;
  int p = atomicAdd(&g_cur[dst[e]], 1);
  g_eidx[p] = (((unsigned)src[e]) << 2) | (unsigned)et[e];
}

__global__ void k_segoff(const int* __restrict__ seg) {
  int n = blockIdx.x * 256 + threadIdx.x;
  if (n >= N_NODESC) return;
  int g = seg[n];
  int gp = (n == 0) ? -1 : seg[n - 1];
  for (int t = gp + 1; t <= g; ++t) g_soff[t] = n;
  if (n == N_NODESC - 1)
    for (int t = g + 1; t <= NGRAPH; ++t) g_soff[t] = N_NODESC;
}

// ---------------- per-step kernels ----------------

#define ACC_ET(hv, et)                                                        \
  {                                                                           \
    float x0 = bf2f(hv[0]), x1 = bf2f(hv[1]), x2 = bf2f(hv[2]), x3 = bf2f(hv[3]); \
    if (et == 0)      { a0[0] += x0; a0[1] += x1; a0[2] += x2; a0[3] += x3; } \
    else if (et == 1) { a1[0] += x0; a1[1] += x1; a1[2] += x2; a1[3] += x3; } \
    else              { a2[0] += x0; a2[1] += x1; a2[2] += x2; a2[3] += x3; } \
  }

// p[n, e*256+d] = sum over in-edges of type e of h_cur[src, d]; one wave per node.
__global__ __launch_bounds__(256) void k_agg(int hoff) {
  int node = blockIdx.x * 4 + (threadIdx.x >> 6);
  int lane = threadIdx.x & 63;
  if (node >= N_NODESC) return;
  float a0[4] = {0.f, 0.f, 0.f, 0.f};
  float a1[4] = {0.f, 0.f, 0.f, 0.f};
  float a2[4] = {0.f, 0.f, 0.f, 0.f};
  int s = g_rowoff[node], e = g_rowoff[node + 1];
  int i = s;
  for (; i + 4 <= e; i += 4) {
    unsigned v0 = g_eidx[i], v1 = g_eidx[i + 1], v2 = g_eidx[i + 2], v3 = g_eidx[i + 3];
    u16x4 hv0 = *(const u16x4*)(g_ah + (size_t)(v0 >> 2) * 768 + hoff + lane * 4);
    u16x4 hv1 = *(const u16x4*)(g_ah + (size_t)(v1 >> 2) * 768 + hoff + lane * 4);
    u16x4 hv2 = *(const u16x4*)(g_ah + (size_t)(v2 >> 2) * 768 + hoff + lane * 4);
    u16x4 hv3 = *(const u16x4*)(g_ah + (size_t)(v3 >> 2) * 768 + hoff + lane * 4);
    int e0 = (int)(v0 & 3u), e1 = (int)(v1 & 3u), e2 = (int)(v2 & 3u), e3 = (int)(v3 & 3u);
    ACC_ET(hv0, e0);
    ACC_ET(hv1, e1);
    ACC_ET(hv2, e2);
    ACC_ET(hv3, e3);
  }
  for (; i < e; ++i) {
    unsigned v = g_eidx[i];
    u16x4 hv = *(const u16x4*)(g_ah + (size_t)(v >> 2) * 768 + hoff + lane * 4);
    int et = (int)(v & 3u);
    ACC_ET(hv, et);
  }
  size_t base = (size_t)node * DIM3 + lane * 4;
  u16x4 o0 = {f2bf(a0[0]), f2bf(a0[1]), f2bf(a0[2]), f2bf(a0[3])};
  u16x4 o1 = {f2bf(a1[0]), f2bf(a1[1]), f2bf(a1[2]), f2bf(a1[3])};
  u16x4 o2 = {f2bf(a2[0]), f2bf(a2[1]), f2bf(a2[2]), f2bf(a2[3])};
  *(u16x4*)(g_p + base)       = o0;
  *(u16x4*)(g_p + base + 256) = o1;
  *(u16x4*)(g_p + base + 512) = o2;
}

// a-part of g_ah = g_p @ g_Wc^T + cnt*b_msg  (R6-proven single-buffer body,
// XCD-banded BX=2 as verified in R13).
__global__ __launch_bounds__(256) void k_gemm0(const float* __restrict__ bmsg) {
  constexpr int K = DIM3;
  __shared__ unsigned short lA[128 * 64];
  __shared__ unsigned short lB[128 * 64];
  const int tx = threadIdx.x;
  const int lane = tx & 63;
  const int wave = tx >> 6;
  const int wr = wave >> 1, wc = wave & 1;
  const int bid = blockIdx.x + blockIdx.y * 2;   // grid dim3(2, 392)
  const int xcd = bid & 7, ii = bid >> 3;        // ii in [0, 98)
  const int tileM = (xcd * 49 + (ii >> 1)) * 128;
  const int tileN = (ii & 1) * 128;

  f32x4 acc[4][4];
#pragma unroll
  for (int m = 0; m < 4; ++m)
#pragma unroll
    for (int n = 0; n < 4; ++n) {
      acc[m][n][0] = 0.f; acc[m][n][1] = 0.f; acc[m][n][2] = 0.f; acc[m][n][3] = 0.f;
    }

  const int f = lane & 15, q = lane >> 4, xr = f & 7;

  int srow[4], scg[4];
#pragma unroll
  for (int i = 0; i < 4; ++i) {
    int byteo = i * 4096 + tx * 16;
    srow[i] = byteo >> 7;
    scg[i] = ((byteo >> 4) & 7) ^ (srow[i] & 7);
  }

  for (int k0 = 0; k0 < K; k0 += 64) {
#pragma unroll
    for (int i = 0; i < 4; ++i) {
      int byteo = i * 4096 + tx * 16;
      async16((const void*)(g_p + (size_t)(tileM + srow[i]) * K + k0 + scg[i] * 8),
              (void*)((char*)lA + byteo));
      async16((const void*)(g_Wc + (size_t)(tileN + srow[i]) * K + k0 + scg[i] * 8),
              (void*)((char*)lB + byteo));
    }
    __syncthreads();
#pragma unroll
    for (int kk = 0; kk < 2; ++kk) {
      short8 af[4], bfr[4];
#pragma unroll
      for (int m = 0; m < 4; ++m)
        af[m] = *(const short8*)((const char*)lA +
                 (wr * 64 + m * 16 + f) * 128 + (((kk * 4 + q) ^ xr) * 16));
#pragma unroll
      for (int n = 0; n < 4; ++n)
        bfr[n] = *(const short8*)((const char*)lB +
                 (wc * 64 + n * 16 + f) * 128 + (((kk * 4 + q) ^ xr) * 16));
#pragma unroll
      for (int m = 0; m < 4; ++m)
#pragma unroll
        for (int n = 0; n < 4; ++n)
          acc[m][n] = __builtin_amdgcn_mfma_f32_16x16x32_bf16(af[m], bfr[n], acc[m][n], 0, 0, 0);
    }
    __syncthreads();
  }

#pragma unroll
  for (int m = 0; m < 4; ++m) {
    int row0 = tileM + wr * 64 + m * 16 + q * 4;
#pragma unroll
    for (int n = 0; n < 4; ++n) {
      int col = tileN + wc * 64 + n * 16 + f;
      f32x4 v = acc[m][n];
#pragma unroll
      for (int r = 0; r < 4; ++r) {
        int row = row0 + r;
        const int* c = g_cnt + (size_t)row * 4;
        float val = v[r] + c[0] * bmsg[col] + c[1] * bmsg[256 + col] + c[2] * bmsg[512 + col];
        g_ah[(size_t)row * 768 + col] = f2bf(val);
      }
    }
  }
}

// Fused gates GEMM + GRU. Block = 128 rows x dim-group g (64 dims = 4x64
// permuted WC3 cols). Wave w owns rows [w*32,w*32+32) x ALL 256 cols
// (acc[2][16]); for dim d = g*64+j*16+f the four gate pieces live at
// acc[m][{0,4,8,12}+j] -> SAME lane/reg: GRU fully in-register. Reads
// A = [a | h_cur] (uniform col-base per K-step), writes h_next + g_hf.
// XCD-banded: 49 row-tiles x 4 groups per XCD; A row-tile reused in its L2.
__global__ __launch_bounds__(256, 1) void k_gemmCG(const float* __restrict__ bih,
                                                   const float* __restrict__ bhh,
                                                   int hcur, int hnxt) {
  __shared__ unsigned short lA[128 * 64];   // 16 KB
  __shared__ unsigned short lB[256 * 64];   // 32 KB
  const int tx = threadIdx.x;
  const int lane = tx & 63;
  const int w = tx >> 6;
  const int bid = blockIdx.x + blockIdx.y * 4;   // grid dim3(4, 392)
  const int xcd = bid & 7, ii = bid >> 3;        // ii in [0, 196)
  const int tileM = (xcd * 49 + (ii >> 2)) * 128;
  const int g = ii & 3;
  const int f = lane & 15, q = lane >> 4, xr = f & 7;

  f32x4 acc[2][16];
#pragma unroll
  for (int m = 0; m < 2; ++m)
#pragma unroll
    for (int n = 0; n < 16; ++n) {
      acc[m][n][0] = 0.f; acc[m][n][1] = 0.f; acc[m][n][2] = 0.f; acc[m][n][3] = 0.f;
    }

  for (int k0 = 0; k0 < 512; k0 += 64) {
    const int colbase = (k0 < 256) ? k0 : hcur + (k0 - 256);
#pragma unroll
    for (int i = 0; i < 4; ++i) {            // stage A: 128x64
      int byteo = i * 4096 + tx * 16;
      int row = byteo >> 7;
      int cg = ((byteo >> 4) & 7) ^ (row & 7);
      async16((const void*)(g_ah + (size_t)(tileM + row) * 768 + colbase + cg * 8),
              (void*)((char*)lA + byteo));
    }
#pragma unroll
    for (int i = 0; i < 8; ++i) {            // stage B: 256x64 (WC3 rows g*256..)
      int byteo = i * 4096 + tx * 16;
      int row = byteo >> 7;
      int cg = ((byteo >> 4) & 7) ^ (row & 7);
      async16((const void*)(g_WC3 + (size_t)(g * 256 + row) * 512 + k0 + cg * 8),
              (void*)((char*)lB + byteo));
    }
    __syncthreads();
#pragma unroll
    for (int kk = 0; kk < 2; ++kk) {
      int coff = ((kk * 4 + q) ^ xr) * 16;
      short8 af0 = *(const short8*)((const char*)lA + (w * 32 + f) * 128 + coff);
      short8 af1 = *(const short8*)((const char*)lA + (w * 32 + 16 + f) * 128 + coff);
#pragma unroll
      for (int n = 0; n < 16; ++n) {
        short8 b = *(const short8*)((const char*)lB + (n * 16 + f) * 128 + coff);
        acc[0][n] = __builtin_amdgcn_mfma_f32_16x16x32_bf16(af0, b, acc[0][n], 0, 0, 0);
        acc[1][n] = __builtin_amdgcn_mfma_f32_16x16x32_bf16(af1, b, acc[1][n], 0, 0, 0);
      }
    }
    __syncthreads();
  }

#pragma unroll
  for (int m = 0; m < 2; ++m) {
#pragma unroll
    for (int j = 0; j < 4; ++j) {
      int d = g * 64 + j * 16 + f;
      float bR = bih[d] + bhh[d];
      float bZ = bih[256 + d] + bhh[256 + d];
      float bN = bih[512 + d];
      float bH = bhh[512 + d];
#pragma unroll
      for (int r = 0; r < 4; ++r) {
        int row = tileM + w * 32 + m * 16 + q * 4 + r;
        float rr = sigm(acc[m][j][r] + bR);
        float zz = sigm(acc[m][4 + j][r] + bZ);
        float nn = tanhf(acc[m][8 + j][r] + bN + rr * (acc[m][12 + j][r] + bH));
        float ho = g_hf[(size_t)row * DIM + d];
        float o = (1.f - zz) * nn + zz * ho;
        g_hf[(size_t)row * DIM + d] = o;
        g_ah[(size_t)row * 768 + hnxt + d] = f2bf(o);
      }
    }
  }
}

// Gate logits after the last step: one wave per node, shuffle-reduced dot.
__global__ void k_gate(const float* __restrict__ gw, const float* __restrict__ gb) {
  int node = blockIdx.x * 4 + (threadIdx.x >> 6);
  int lane = threadIdx.x & 63;
  if (node >= N_NODESC) return;
  float4 h = *(const float4*)(g_hf + (size_t)node * DIM + lane * 4);
  float4 w = *(const float4*)(gw + lane * 4);
  float p = h.x * w.x + h.y * w.y + h.z * w.z + h.w * w.w;
  for (int o = 32; o > 0; o >>= 1) p += __shfl_xor(p, o);
  if (lane == 0) g_gate[node] = p + gb[0];
}

// ---------------- pooling ----------------

// Per-graph softmax max + denom (gate array is only 200 KB; 64 blocks).
__global__ void k_segred() {
  int g = blockIdx.x, t = threadIdx.x;
  __shared__ float red[256];
  int s = g_soff[g], e = g_soff[g + 1];
  float m = -3.4e38f;
  for (int n = s + t; n < e; n += 256) m = fmaxf(m, g_gate[n]);
  red[t] = m;
  __syncthreads();
  for (int o = 128; o > 0; o >>= 1) {
    if (t < o) red[t] = fmaxf(red[t], red[t + o]);
    __syncthreads();
  }
  m = red[0];
  __syncthreads();
  float sm = 0.f;
  for (int n = s + t; n < e; n += 256) sm += expf(g_gate[n] - m);
  red[t] = sm;
  __syncthreads();
  for (int o = 128; o > 0; o >>= 1) {
    if (t < o) red[t] += red[t + o];
    __syncthreads();
  }
  if (t == 0) {
    g_gmax[g] = m;
    g_gden[g] = (e > s && red[0] != 0.f) ? red[0] : 1.f;
  }
}

__global__ void k_zero_out(float* __restrict__ out) {
  out[blockIdx.x * 256 + threadIdx.x] = 0.f;   // 64*256 = NGRAPH*DIM
}

// 391 blocks x 128 nodes; thread t owns output dim t. seg_ids sorted ->
// accumulate and flush on graph boundary with one atomicAdd per (block,graph).
__global__ __launch_bounds__(256) void k_poolacc(const int* __restrict__ seg,
                                                 float* __restrict__ out) {
  __shared__ int   segL[128];
  __shared__ float alphaL[128];
  int base = blockIdx.x * 128;
  int t = threadIdx.x;
  if (t < 128) {
    int n = base + t;
    if (n < N_NODESC) {
      int g = seg[n];
      segL[t] = g;
      alphaL[t] = expf(g_gate[n] - g_gmax[g]) / g_gden[g];
    } else {
      segL[t] = -1;
    }
  }
  __syncthreads();
  float acc = 0.f;
  int gcur = segL[0];
  for (int j = 0; j < 128; ++j) {
    int gs = segL[j];
    if (gs < 0) break;
    if (gs != gcur) {
      atomicAdd(out + (size_t)gcur * DIM + t, acc);
      acc = 0.f;
      gcur = gs;
    }
    acc += alphaL[j] * g_hf[(size_t)(base + j) * DIM + t];
  }
  if (gcur >= 0) atomicAdd(out + (size_t)gcur * DIM + t, acc);
}

// ---------------- launch ----------------

extern "C" void kernel_launch(void* const* d_in, const int* in_sizes, int n_in,
                              void* d_out, int out_size, void* d_ws, size_t ws_size,
                              hipStream_t stream) {
  const int* x = (const int*)d_in[0];
  const int* src = (const int*)d_in[1];
  const int* dst = (const int*)d_in[2];
  const int* ety = (const int*)d_in[3];
  const int* seg = (const int*)d_in[4];
  const float* emb = (const float*)d_in[6];
  const float* Wmsg = (const float*)d_in[7];
  const float* bmsg = (const float*)d_in[8];
  const float* wih = (const float*)d_in[9];
  const float* whh = (const float*)d_in[10];
  const float* bih = (const float*)d_in[11];
  const float* bhh = (const float*)d_in[12];
  const float* gw = (const float*)d_in[13];
  const float* gb = (const float*)d_in[14];
  float* out = (float*)d_out;

  k_zero_cnt<<<NPAD2 * 4 / 256, 256, 0, stream>>>();
  k_prep_w<<<2816, 256, 0, stream>>>(Wmsg, wih, whh);
  k_embed<<<12500, 256, 0, stream>>>(x, emb);
  k_count<<<(N_EDGESC + 255) / 256, 256, 0, stream>>>(dst, ety);
  k_scan1<<<196, 256, 0, stream>>>();
  k_scan2<<<1, 256, 0, stream>>>();
  k_scan3<<<196, 256, 0, stream>>>();
  k_fill<<<(N_EDGESC + 255) / 256, 256, 0, stream>>>(src, dst, ety);
  k_segoff<<<196, 256, 0, stream>>>(seg);

  for (int s = 0; s < NSTEPS; ++s) {
    int hcur = 256 + (s & 1) * 256;
    int hnxt = 256 + ((s + 1) & 1) * 256;
    k_agg<<<12500, 256, 0, stream>>>(hcur);
    k_gemm0<<<dim3(2, 392), 256, 0, stream>>>(bmsg);
    k_gemmCG<<<dim3(4, 392), 256, 0, stream>>>(bih, bhh, hcur, hnxt);
  }

  k_gate<<<12500, 256, 0, stream>>>(gw, gb);
  k_segred<<<NGRAPH, 256, 0, stream>>>();
  k_zero_out<<<NGRAPH, 256, 0, stream>>>(out);
  k_poolacc<<<391, 256, 0, stream>>>(seg, out);
}

// Round 15
// 1343.437 us; speedup vs baseline: 1.2912x; 1.2912x over previous
//
#include <hip/hip_runtime.h>
#include <hip/hip_bf16.h>
#include <stdint.h>

#define N_NODESC 50000
#define NPAD     50048   // 391 * 128
#define NPAD2    50176   // 392 * 128 (8 XCD bands x 49 row-tiles)
#define N_EDGESC 800000
#define DIM      256
#define DIM3     768
#define NSTEPS   5
#define NGRAPH   64

typedef __attribute__((ext_vector_type(4))) float  f32x4;
typedef __attribute__((ext_vector_type(8))) short  short8;
typedef __attribute__((ext_vector_type(4))) unsigned short u16x4;
typedef __attribute__((ext_vector_type(4))) _Float16 f16x4;

// ---------------- device-global scratch (no d_ws dependence) ----------------
__device__ float          g_hf[(size_t)NPAD2 * DIM];
__device__ unsigned short g_ah[(size_t)NPAD2 * 512];     // [a(256) | h_bf16(256)] per row
__device__ unsigned short g_p [(size_t)NPAD2 * DIM3];
__device__ _Float16       g_gates[(size_t)NPAD2 * 1024]; // [rz_sum(512) | i_n(256) | h_n(256)]
__device__ unsigned short g_Wc[DIM * DIM3];
// g_WC2: [0,262144): rz rows c<512, K=512 = [wih[c] | whh[c]]
//        [262144,327680): i_n rows c<256, K=256 = wih[512+c]
//        [327680,393216): h_n rows c<256, K=256 = whh[512+c]
__device__ unsigned short g_WC2[393216];
__device__ float          g_biasC[1024];
__device__ int            g_cnt[NPAD2 * 4];
__device__ int            g_rowoff[N_NODESC + 1];
__device__ int            g_cur[N_NODESC];
__device__ unsigned       g_eidx[N_EDGESC];
__device__ int            g_bsum[256];
__device__ int            g_boff[256];
__device__ float          g_gate[N_NODESC];
__device__ int            g_soff[NGRAPH + 1];
__device__ float          g_gmax[NGRAPH];
__device__ float          g_gden[NGRAPH];

__device__ __forceinline__ float bf2f(unsigned short u) {
  unsigned x = ((unsigned)u) << 16;
  return __builtin_bit_cast(float, x);
}
__device__ __forceinline__ unsigned short f2bf(float f) {
  unsigned u = __builtin_bit_cast(unsigned, f);
  u += 0x7fffu + ((u >> 16) & 1u);
  return (unsigned short)(u >> 16);
}
__device__ __forceinline__ float sigm(float x) { return 1.0f / (1.0f + expf(-x)); }

__device__ __forceinline__ void async16(const void* g, void* l) {
  __builtin_amdgcn_global_load_lds(
      (const __attribute__((address_space(1))) unsigned int*)g,
      (__attribute__((address_space(3))) unsigned int*)l, 16, 0, 0);
}

// ---------------- once-per-launch prep ----------------

__global__ void k_zero_cnt() {
  int i = blockIdx.x * 256 + threadIdx.x;   // NPAD2*4 = 200704 = 784*256
  g_cnt[i] = 0;
}

// Wc[f][e*256+d] = W_msg[e][d][f]; WC2 per the layout comment above;
// biasC[c] = bih[c]+bhh[c] (c<512) | bih[c] (512..768) | bhh[c-256] (768..1024).
__global__ void k_prep_w(const float* __restrict__ Wmsg, const float* __restrict__ wih,
                         const float* __restrict__ whh, const float* __restrict__ bih,
                         const float* __restrict__ bhh) {
  int i = blockIdx.x * 256 + threadIdx.x;   // 590848 = 2308*256
  if (i < 196608) {
    int f = i / 768, j = i - f * 768;      // j = e*256 + d
    int e = j >> 8, d = j & 255;
    g_Wc[i] = f2bf(Wmsg[(e << 16) + (d << 8) + f]);
  } else if (i < 589824) {
    int t = i - 196608;
    float v;
    if (t < 262144) {
      int c = t >> 9, k = t & 511;
      v = (k < 256) ? wih[c * 256 + k] : whh[c * 256 + (k - 256)];
    } else if (t < 327680) {
      int t2 = t - 262144;
      int c = t2 >> 8, k = t2 & 255;
      v = wih[(512 + c) * 256 + k];
    } else {
      int t3 = t - 327680;
      int c = t3 >> 8, k = t3 & 255;
      v = whh[(512 + c) * 256 + k];
    }
    g_WC2[t] = f2bf(v);
  } else if (i < 590848) {
    int c = i - 589824;
    float v;
    if (c < 512)      v = bih[c] + bhh[c];
    else if (c < 768) v = bih[c];
    else              v = bhh[c - 256];
    g_biasC[c] = v;
  }
}

__global__ void k_embed(const int* __restrict__ x, const float* __restrict__ emb) {
  int i = blockIdx.x * 256 + threadIdx.x;        // N_NODESC*64 total
  int n = i >> 6, t = i & 63;
  if (n >= N_NODESC) return;
  float4 v = *(const float4*)(emb + (size_t)x[n] * DIM + t * 4);
  *(float4*)(g_hf + (size_t)n * DIM + t * 4) = v;
  u16x4 b = {f2bf(v.x), f2bf(v.y), f2bf(v.z), f2bf(v.w)};
  *(u16x4*)(g_ah + (size_t)n * 512 + 256 + t * 4) = b;
}

__global__ void k_count(const int* __restrict__ dst, const int* __restrict__ et) {
  int e = blockIdx.x * 256 + threadIdx.x;
  if (e >= N_EDGESC) return;
  atomicAdd(&g_cnt[dst[e] * 4 + et[e]], 1);
}

__global__ void k_scan1() {
  __shared__ int lds[256];
  int n = blockIdx.x * 256 + threadIdx.x;
  int deg = (n < N_NODESC) ? (g_cnt[n * 4] + g_cnt[n * 4 + 1] + g_cnt[n * 4 + 2]) : 0;
  lds[threadIdx.x] = deg;
  __syncthreads();
  for (int o = 128; o > 0; o >>= 1) {
    if (threadIdx.x < o) lds[threadIdx.x] += lds[threadIdx.x + o];
    __syncthreads();
  }
  if (threadIdx.x == 0) g_bsum[blockIdx.x] = lds[0];
}

__global__ void k_scan2() {
  __shared__ int lds[256];
  int t = threadIdx.x;
  int v = (t < 196) ? g_bsum[t] : 0;
  lds[t] = v;
  __syncthreads();
  for (int o = 1; o < 256; o <<= 1) {
    int u = (t >= o) ? lds[t - o] : 0;
    __syncthreads();
    lds[t] += u;
    __syncthreads();
  }
  if (t < 196) g_boff[t] = lds[t] - v;   // exclusive
}

__global__ void k_scan3() {
  __shared__ int lds[256];
  int n = blockIdx.x * 256 + threadIdx.x;
  int t = threadIdx.x;
  int deg = (n < N_NODESC) ? (g_cnt[n * 4] + g_cnt[n * 4 + 1] + g_cnt[n * 4 + 2]) : 0;
  lds[t] = deg;
  __syncthreads();
  for (int o = 1; o < 256; o <<= 1) {
    int u = (t >= o) ? lds[t - o] : 0;
    __syncthreads();
    lds[t] += u;
    __syncthreads();
  }
  if (n < N_NODESC) {
    int off = g_boff[blockIdx.x] + lds[t] - deg;
    g_rowoff[n] = off;
    g_cur[n] = off;
  }
  if (n == N_NODESC - 1) g_rowoff[N_NODESC] = g_boff[blockIdx.x] + lds[t];
}

__global__ void k_fill(const int* __restrict__ src, const int* __restrict__ dst,
                       const int* __restrict__ et) {
  int e = blockIdx.x * 256 + threadIdx.x;
  if (e >= N_EDGESC) return;
  int p = atomicAdd(&g_cur[dst[e]], 1);
  g_eidx[p] = (((unsigned)src[e]) << 2) | (unsigned)et[e];
}

__global__ void k_segoff(const int* __restrict__ seg) {
  int n = blockIdx.x * 256 + threadIdx.x;
  if (n >= N_NODESC) return;
  int g = seg[n];
  int gp = (n == 0) ? -1 : seg[n - 1];
  for (int t = gp + 1; t <= g; ++t) g_soff[t] = n;
  if (n == N_NODESC - 1)
    for (int t = g + 1; t <= NGRAPH; ++t) g_soff[t] = N_NODESC;
}

// ---------------- per-step kernels ----------------

#define ACC_ET(hv, et)                                                        \
  {                                                                           \
    float x0 = bf2f(hv[0]), x1 = bf2f(hv[1]), x2 = bf2f(hv[2]), x3 = bf2f(hv[3]); \
    if (et == 0)      { a0[0] += x0; a0[1] += x1; a0[2] += x2; a0[3] += x3; } \
    else if (et == 1) { a1[0] += x0; a1[1] += x1; a1[2] += x2; a1[3] += x3; } \
    else              { a2[0] += x0; a2[1] += x1; a2[2] += x2; a2[3] += x3; } \
  }

// p[n, e*256+d] = sum over in-edges of type e of h_bf16[src, d]; one wave per node.
__global__ __launch_bounds__(256) void k_agg() {
  int node = blockIdx.x * 4 + (threadIdx.x >> 6);
  int lane = threadIdx.x & 63;
  if (node >= N_NODESC) return;
  float a0[4] = {0.f, 0.f, 0.f, 0.f};
  float a1[4] = {0.f, 0.f, 0.f, 0.f};
  float a2[4] = {0.f, 0.f, 0.f, 0.f};
  int s = g_rowoff[node], e = g_rowoff[node + 1];
  int i = s;
  for (; i + 4 <= e; i += 4) {
    unsigned v0 = g_eidx[i], v1 = g_eidx[i + 1], v2 = g_eidx[i + 2], v3 = g_eidx[i + 3];
    u16x4 hv0 = *(const u16x4*)(g_ah + (size_t)(v0 >> 2) * 512 + 256 + lane * 4);
    u16x4 hv1 = *(const u16x4*)(g_ah + (size_t)(v1 >> 2) * 512 + 256 + lane * 4);
    u16x4 hv2 = *(const u16x4*)(g_ah + (size_t)(v2 >> 2) * 512 + 256 + lane * 4);
    u16x4 hv3 = *(const u16x4*)(g_ah + (size_t)(v3 >> 2) * 512 + 256 + lane * 4);
    int e0 = (int)(v0 & 3u), e1 = (int)(v1 & 3u), e2 = (int)(v2 & 3u), e3 = (int)(v3 & 3u);
    ACC_ET(hv0, e0);
    ACC_ET(hv1, e1);
    ACC_ET(hv2, e2);
    ACC_ET(hv3, e3);
  }
  for (; i < e; ++i) {
    unsigned v = g_eidx[i];
    u16x4 hv = *(const u16x4*)(g_ah + (size_t)(v >> 2) * 512 + 256 + lane * 4);
    int et = (int)(v & 3u);
    ACC_ET(hv, et);
  }
  size_t base = (size_t)node * DIM3 + lane * 4;
  u16x4 o0 = {f2bf(a0[0]), f2bf(a0[1]), f2bf(a0[2]), f2bf(a0[3])};
  u16x4 o1 = {f2bf(a1[0]), f2bf(a1[1]), f2bf(a1[2]), f2bf(a1[3])};
  u16x4 o2 = {f2bf(a2[0]), f2bf(a2[1]), f2bf(a2[2]), f2bf(a2[3])};
  *(u16x4*)(g_p + base)       = o0;
  *(u16x4*)(g_p + base + 256) = o1;
  *(u16x4*)(g_p + base + 512) = o2;
}

// a-part of g_ah = g_p @ g_Wc^T + cnt*b_msg  (R6-proven single-buffer body,
// XCD-banded BX=2 as HW-verified in R13).
__global__ __launch_bounds__(256) void k_gemm0(const float* __restrict__ bmsg) {
  constexpr int K = DIM3;
  __shared__ unsigned short lA[128 * 64];
  __shared__ unsigned short lB[128 * 64];
  const int tx = threadIdx.x;
  const int lane = tx & 63;
  const int wave = tx >> 6;
  const int wr = wave >> 1, wc = wave & 1;
  const int bid = blockIdx.x + blockIdx.y * 2;   // grid dim3(2, 392)
  const int xcd = bid & 7, ii = bid >> 3;        // ii in [0, 98)
  const int tileM = (xcd * 49 + (ii >> 1)) * 128;
  const int tileN = (ii & 1) * 128;

  f32x4 acc[4][4];
#pragma unroll
  for (int m = 0; m < 4; ++m)
#pragma unroll
    for (int n = 0; n < 4; ++n) {
      acc[m][n][0] = 0.f; acc[m][n][1] = 0.f; acc[m][n][2] = 0.f; acc[m][n][3] = 0.f;
    }

  const int f = lane & 15, q = lane >> 4, xr = f & 7;

  int srow[4], scg[4];
#pragma unroll
  for (int i = 0; i < 4; ++i) {
    int byteo = i * 4096 + tx * 16;
    srow[i] = byteo >> 7;
    scg[i] = ((byteo >> 4) & 7) ^ (srow[i] & 7);
  }

  for (int k0 = 0; k0 < K; k0 += 64) {
#pragma unroll
    for (int i = 0; i < 4; ++i) {
      int byteo = i * 4096 + tx * 16;
      async16((const void*)(g_p + (size_t)(tileM + srow[i]) * K + k0 + scg[i] * 8),
              (void*)((char*)lA + byteo));
      async16((const void*)(g_Wc + (size_t)(tileN + srow[i]) * K + k0 + scg[i] * 8),
              (void*)((char*)lB + byteo));
    }
    __syncthreads();
#pragma unroll
    for (int kk = 0; kk < 2; ++kk) {
      short8 af[4], bfr[4];
#pragma unroll
      for (int m = 0; m < 4; ++m)
        af[m] = *(const short8*)((const char*)lA +
                 (wr * 64 + m * 16 + f) * 128 + (((kk * 4 + q) ^ xr) * 16));
#pragma unroll
      for (int n = 0; n < 4; ++n)
        bfr[n] = *(const short8*)((const char*)lB +
                 (wc * 64 + n * 16 + f) * 128 + (((kk * 4 + q) ^ xr) * 16));
#pragma unroll
      for (int m = 0; m < 4; ++m)
#pragma unroll
        for (int n = 0; n < 4; ++n)
          acc[m][n] = __builtin_amdgcn_mfma_f32_16x16x32_bf16(af[m], bfr[n], acc[m][n], 0, 0, 0);
    }
    __syncthreads();
  }

#pragma unroll
  for (int m = 0; m < 4; ++m) {
    int row0 = tileM + wr * 64 + m * 16 + q * 4;
#pragma unroll
    for (int n = 0; n < 4; ++n) {
      int col = tileN + wc * 64 + n * 16 + f;
      f32x4 v = acc[m][n];
#pragma unroll
      for (int r = 0; r < 4; ++r) {
        int row = row0 + r;
        const int* c = g_cnt + (size_t)row * 4;
        float val = v[r] + c[0] * bmsg[col] + c[1] * bmsg[256 + col] + c[2] * bmsg[512 + col];
        g_ah[(size_t)row * 512 + col] = f2bf(val);
      }
    }
  }
}

// Shared gemmC body (R6/R13-proven staged+swizzled 128x128 tile).
// K, BSTRIDE compile-time; A read from g_ah cols [acol0, acol0+K);
// B rows [brow0, brow0+128) of Bbase (stride BSTRIDE); writes gates cols
// [outcol0, outcol0+128) with biasC.
template <int K, int BSTRIDE>
__device__ __forceinline__ void gemmC_body(unsigned short* lA, unsigned short* lB,
                                           const unsigned short* __restrict__ Bbase,
                                           int tileM, int brow0, int outcol0, int acol0) {
  const int tx = threadIdx.x;
  const int lane = tx & 63;
  const int wave = tx >> 6;
  const int wr = wave >> 1, wc = wave & 1;
  const int f = lane & 15, q = lane >> 4, xr = f & 7;

  f32x4 acc[4][4];
#pragma unroll
  for (int m = 0; m < 4; ++m)
#pragma unroll
    for (int n = 0; n < 4; ++n) {
      acc[m][n][0] = 0.f; acc[m][n][1] = 0.f; acc[m][n][2] = 0.f; acc[m][n][3] = 0.f;
    }

  int srow[4], scg[4];
#pragma unroll
  for (int i = 0; i < 4; ++i) {
    int byteo = i * 4096 + tx * 16;
    srow[i] = byteo >> 7;
    scg[i] = ((byteo >> 4) & 7) ^ (srow[i] & 7);
  }

  for (int k0 = 0; k0 < K; k0 += 64) {
#pragma unroll
    for (int i = 0; i < 4; ++i) {
      int byteo = i * 4096 + tx * 16;
      async16((const void*)(g_ah + (size_t)(tileM + srow[i]) * 512 + acol0 + k0 + scg[i] * 8),
              (void*)((char*)lA + byteo));
      async16((const void*)(Bbase + (size_t)(brow0 + srow[i]) * BSTRIDE + k0 + scg[i] * 8),
              (void*)((char*)lB + byteo));
    }
    __syncthreads();
#pragma unroll
    for (int kk = 0; kk < 2; ++kk) {
      short8 af[4], bfr[4];
#pragma unroll
      for (int m = 0; m < 4; ++m)
        af[m] = *(const short8*)((const char*)lA +
                 (wr * 64 + m * 16 + f) * 128 + (((kk * 4 + q) ^ xr) * 16));
#pragma unroll
      for (int n = 0; n < 4; ++n)
        bfr[n] = *(const short8*)((const char*)lB +
                 (wc * 64 + n * 16 + f) * 128 + (((kk * 4 + q) ^ xr) * 16));
#pragma unroll
      for (int m = 0; m < 4; ++m)
#pragma unroll
        for (int n = 0; n < 4; ++n)
          acc[m][n] = __builtin_amdgcn_mfma_f32_16x16x32_bf16(af[m], bfr[n], acc[m][n], 0, 0, 0);
    }
    __syncthreads();
  }

#pragma unroll
  for (int m = 0; m < 4; ++m) {
    int row0 = tileM + wr * 64 + m * 16 + q * 4;
#pragma unroll
    for (int n = 0; n < 4; ++n) {
      int col = outcol0 + wc * 64 + n * 16 + f;
      float bs = g_biasC[col];
#pragma unroll
      for (int r = 0; r < 4; ++r)
        g_gates[(size_t)(row0 + r) * 1024 + col] = (_Float16)(acc[m][n][r] + bs);
    }
  }
}

// Combined gate GEMM, heterogeneous K per col-tile region:
//  ct 0-3: rz (K=512 concat [a|h], pre-summed WI+WH products)
//  ct 4-5: i_n (K=256, a-half only)   ct 6-7: h_n (K=256, h-half only)
// XCD-banded (R13-verified): the 8 col-tiles of one A row-tile run on ONE XCD.
__global__ __launch_bounds__(256) void k_gemmC() {
  __shared__ unsigned short lA[128 * 64];
  __shared__ unsigned short lB[128 * 64];
  const int bid = blockIdx.x + blockIdx.y * 8;   // grid dim3(8, 392)
  const int xcd = bid & 7, ii = bid >> 3;        // ii in [0, 392)
  const int tileM = (xcd * 49 + (ii >> 3)) * 128;
  const int ct = ii & 7;
  if (ct < 4)
    gemmC_body<512, 512>(lA, lB, g_WC2, tileM, ct * 128, ct * 128, 0);
  else if (ct < 6)
    gemmC_body<256, 256>(lA, lB, g_WC2 + 262144, tileM, (ct - 4) * 128, ct * 128, 0);
  else
    gemmC_body<256, 256>(lA, lB, g_WC2 + 327680, tileM, (ct - 6) * 128, ct * 128, 256);
}

// GRU elementwise from combined gates. LAST=1 additionally computes the
// attention-gate logit per node (one 64-lane wave per node; shuffle-reduce).
template <int LAST>
__global__ void k_gru(const float* __restrict__ gw, const float* __restrict__ gb) {
  int i = blockIdx.x * 256 + threadIdx.x;   // N_NODESC*64
  int n = i >> 6, t = (i & 63) * 4;
  if (n >= N_NODESC) return;
  size_t bg = (size_t)n * 1024 + t;
  size_t b1 = (size_t)n * DIM + t;
  f16x4 rz_r = *(const f16x4*)(g_gates + bg);
  f16x4 rz_z = *(const f16x4*)(g_gates + bg + 256);
  f16x4 in4  = *(const f16x4*)(g_gates + bg + 512);
  f16x4 hn4  = *(const f16x4*)(g_gates + bg + 768);
  float4 h = *(const float4*)(g_hf + b1);
  float4 o;
#pragma unroll
  for (int j = 0; j < 4; ++j) {
    float r = sigm((float)rz_r[j]);
    float z = sigm((float)rz_z[j]);
    float nn = tanhf((float)in4[j] + r * (float)hn4[j]);
    float hj = (j == 0) ? h.x : (j == 1) ? h.y : (j == 2) ? h.z : h.w;
    float oj = (1.f - z) * nn + z * hj;
    if (j == 0) o.x = oj; else if (j == 1) o.y = oj; else if (j == 2) o.z = oj; else o.w = oj;
  }
  *(float4*)(g_hf + b1) = o;
  u16x4 ob = {f2bf(o.x), f2bf(o.y), f2bf(o.z), f2bf(o.w)};
  *(u16x4*)(g_ah + (size_t)n * 512 + 256 + t) = ob;
  if (LAST) {
    float4 w = *(const float4*)(gw + t);
    float p = o.x * w.x + o.y * w.y + o.z * w.z + o.w * w.w;
    for (int off = 32; off > 0; off >>= 1) p += __shfl_xor(p, off);
    if ((threadIdx.x & 63) == 0) g_gate[n] = p + gb[0];
  }
}

// ---------------- pooling ----------------

// Per-graph softmax max + denom (gate array is only 200 KB; 64 blocks).
__global__ void k_segred() {
  int g = blockIdx.x, t = threadIdx.x;
  __shared__ float red[256];
  int s = g_soff[g], e = g_soff[g + 1];
  float m = -3.4e38f;
  for (int n = s + t; n < e; n += 256) m = fmaxf(m, g_gate[n]);
  red[t] = m;
  __syncthreads();
  for (int o = 128; o > 0; o >>= 1) {
    if (t < o) red[t] = fmaxf(red[t], red[t + o]);
    __syncthreads();
  }
  m = red[0];
  __syncthreads();
  float sm = 0.f;
  for (int n = s + t; n < e; n += 256) sm += expf(g_gate[n] - m);
  red[t] = sm;
  __syncthreads();
  for (int o = 128; o > 0; o >>= 1) {
    if (t < o) red[t] += red[t + o];
    __syncthreads();
  }
  if (t == 0) {
    g_gmax[g] = m;
    g_gden[g] = (e > s && red[0] != 0.f) ? red[0] : 1.f;
  }
}

__global__ void k_zero_out(float* __restrict__ out) {
  out[blockIdx.x * 256 + threadIdx.x] = 0.f;   // 64*256 = NGRAPH*DIM
}

// 391 blocks x 128 nodes; thread t owns output dim t. seg_ids sorted ->
// accumulate and flush on graph boundary with one atomicAdd per (block,graph).
__global__ __launch_bounds__(256) void k_poolacc(const int* __restrict__ seg,
                                                 float* __restrict__ out) {
  __shared__ int   segL[128];
  __shared__ float alphaL[128];
  int base = blockIdx.x * 128;
  int t = threadIdx.x;
  if (t < 128) {
    int n = base + t;
    if (n < N_NODESC) {
      int g = seg[n];
      segL[t] = g;
      alphaL[t] = expf(g_gate[n] - g_gmax[g]) / g_gden[g];
    } else {
      segL[t] = -1;
    }
  }
  __syncthreads();
  float acc = 0.f;
  int gcur = segL[0];
  for (int j = 0; j < 128; ++j) {
    int gs = segL[j];
    if (gs < 0) break;
    if (gs != gcur) {
      atomicAdd(out + (size_t)gcur * DIM + t, acc);
      acc = 0.f;
      gcur = gs;
    }
    acc += alphaL[j] * g_hf[(size_t)(base + j) * DIM + t];
  }
  if (gcur >= 0) atomicAdd(out + (size_t)gcur * DIM + t, acc);
}

// ---------------- launch ----------------

extern "C" void kernel_launch(void* const* d_in, const int* in_sizes, int n_in,
                              void* d_out, int out_size, void* d_ws, size_t ws_size,
                              hipStream_t stream) {
  const int* x = (const int*)d_in[0];
  const int* src = (const int*)d_in[1];
  const int* dst = (const int*)d_in[2];
  const int* ety = (const int*)d_in[3];
  const int* seg = (const int*)d_in[4];
  const float* emb = (const float*)d_in[6];
  const float* Wmsg = (const float*)d_in[7];
  const float* bmsg = (const float*)d_in[8];
  const float* wih = (const float*)d_in[9];
  const float* whh = (const float*)d_in[10];
  const float* bih = (const float*)d_in[11];
  const float* bhh = (const float*)d_in[12];
  const float* gw = (const float*)d_in[13];
  const float* gb = (const float*)d_in[14];
  float* out = (float*)d_out;

  k_zero_cnt<<<NPAD2 * 4 / 256, 256, 0, stream>>>();
  k_prep_w<<<2308, 256, 0, stream>>>(Wmsg, wih, whh, bih, bhh);
  k_embed<<<12500, 256, 0, stream>>>(x, emb);
  k_count<<<(N_EDGESC + 255) / 256, 256, 0, stream>>>(dst, ety);
  k_scan1<<<196, 256, 0, stream>>>();
  k_scan2<<<1, 256, 0, stream>>>();
  k_scan3<<<196, 256, 0, stream>>>();
  k_fill<<<(N_EDGESC + 255) / 256, 256, 0, stream>>>(src, dst, ety);
  k_segoff<<<196, 256, 0, stream>>>(seg);

  for (int s = 0; s < NSTEPS; ++s) {
    k_agg<<<12500, 256, 0, stream>>>();
    k_gemm0<<<dim3(2, 392), 256, 0, stream>>>(bmsg);
    k_gemmC<<<dim3(8, 392), 256, 0, stream>>>();
    if (s < NSTEPS - 1)
      k_gru<0><<<12500, 256, 0, stream>>>(nullptr, nullptr);
    else
      k_gru<1><<<12500, 256, 0, stream>>>(gw, gb);
  }

  k_segred<<<NGRAPH, 256, 0, stream>>>();
  k_zero_out<<<NGRAPH, 256, 0, stream>>>(out);
  k_poolacc<<<391, 256, 0, stream>>>(seg, out);
}

// Round 16
// 1340.313 us; speedup vs baseline: 1.2943x; 1.0023x over previous
//
#include <hip/hip_runtime.h>
#include <hip/hip_bf16.h>
#include <stdint.h>

#define N_NODESC 50000
#define NPAD     50048   // 391 * 128
#define NPAD2    50176   // 392 * 128 (8 XCD bands x 49 row-tiles)
#define N_EDGESC 800000
#define DIM      256
#define DIM3     768
#define NSTEPS   5
#define NGRAPH   64

typedef __attribute__((ext_vector_type(4))) float  f32x4;
typedef __attribute__((ext_vector_type(8))) short  short8;
typedef __attribute__((ext_vector_type(4))) unsigned short u16x4;
typedef __attribute__((ext_vector_type(4))) _Float16 f16x4;

// ---------------- device-global scratch (no d_ws dependence) ----------------
__device__ float          g_hf[(size_t)NPAD2 * DIM];
__device__ unsigned short g_ah[(size_t)NPAD2 * 512];     // [a(256) | h_bf16(256)] per row
__device__ unsigned short g_p [(size_t)NPAD2 * DIM3];
__device__ _Float16       g_gates[(size_t)NPAD2 * 1024]; // [rz_sum(512) | i_n(256) | h_n(256)]
__device__ unsigned short g_Wc[DIM * DIM3];
// g_WC2: [0,262144): rz rows c<512, K=512 = [wih[c] | whh[c]]
//        [262144,327680): i_n rows c<256, K=256 = wih[512+c]
//        [327680,393216): h_n rows c<256, K=256 = whh[512+c]
__device__ unsigned short g_WC2[393216];
__device__ float          g_biasC[1024];
__device__ int            g_cnt[NPAD2 * 4];
__device__ int            g_rowoff[N_NODESC + 1];
__device__ int            g_cur[N_NODESC];
__device__ unsigned       g_eidx[N_EDGESC];
__device__ int            g_bsum[256];
__device__ int            g_boff[256];
__device__ float          g_gate[N_NODESC];
__device__ int            g_soff[NGRAPH + 1];
__device__ float          g_gmax[NGRAPH];
__device__ float          g_gden[NGRAPH];

__device__ __forceinline__ float bf2f(unsigned short u) {
  unsigned x = ((unsigned)u) << 16;
  return __builtin_bit_cast(float, x);
}
__device__ __forceinline__ unsigned short f2bf(float f) {
  unsigned u = __builtin_bit_cast(unsigned, f);
  u += 0x7fffu + ((u >> 16) & 1u);
  return (unsigned short)(u >> 16);
}
__device__ __forceinline__ float sigm(float x) { return 1.0f / (1.0f + expf(-x)); }

__device__ __forceinline__ void async16(const void* g, void* l) {
  __builtin_amdgcn_global_load_lds(
      (const __attribute__((address_space(1))) unsigned int*)g,
      (__attribute__((address_space(3))) unsigned int*)l, 16, 0, 0);
}

// ---------------- once-per-launch prep ----------------

__global__ void k_zero_cnt() {
  int i = blockIdx.x * 256 + threadIdx.x;   // NPAD2*4 = 200704 = 784*256
  g_cnt[i] = 0;
}

// Wc[f][e*256+d] = W_msg[e][d][f]; WC2 per the layout comment above;
// biasC[c] = bih[c]+bhh[c] (c<512) | bih[c] (512..768) | bhh[c-256] (768..1024).
__global__ void k_prep_w(const float* __restrict__ Wmsg, const float* __restrict__ wih,
                         const float* __restrict__ whh, const float* __restrict__ bih,
                         const float* __restrict__ bhh) {
  int i = blockIdx.x * 256 + threadIdx.x;   // 590848 = 2308*256
  if (i < 196608) {
    int f = i / 768, j = i - f * 768;      // j = e*256 + d
    int e = j >> 8, d = j & 255;
    g_Wc[i] = f2bf(Wmsg[(e << 16) + (d << 8) + f]);
  } else if (i < 589824) {
    int t = i - 196608;
    float v;
    if (t < 262144) {
      int c = t >> 9, k = t & 511;
      v = (k < 256) ? wih[c * 256 + k] : whh[c * 256 + (k - 256)];
    } else if (t < 327680) {
      int t2 = t - 262144;
      int c = t2 >> 8, k = t2 & 255;
      v = wih[(512 + c) * 256 + k];
    } else {
      int t3 = t - 327680;
      int c = t3 >> 8, k = t3 & 255;
      v = whh[(512 + c) * 256 + k];
    }
    g_WC2[t] = f2bf(v);
  } else if (i < 590848) {
    int c = i - 589824;
    float v;
    if (c < 512)      v = bih[c] + bhh[c];
    else if (c < 768) v = bih[c];
    else              v = bhh[c - 256];
    g_biasC[c] = v;
  }
}

__global__ void k_embed(const int* __restrict__ x, const float* __restrict__ emb) {
  int i = blockIdx.x * 256 + threadIdx.x;        // N_NODESC*64 total
  int n = i >> 6, t = i & 63;
  if (n >= N_NODESC) return;
  float4 v = *(const float4*)(emb + (size_t)x[n] * DIM + t * 4);
  *(float4*)(g_hf + (size_t)n * DIM + t * 4) = v;
  u16x4 b = {f2bf(v.x), f2bf(v.y), f2bf(v.z), f2bf(v.w)};
  *(u16x4*)(g_ah + (size_t)n * 512 + 256 + t * 4) = b;
}

__global__ void k_count(const int* __restrict__ dst, const int* __restrict__ et) {
  int e = blockIdx.x * 256 + threadIdx.x;
  if (e >= N_EDGESC) return;
  atomicAdd(&g_cnt[dst[e] * 4 + et[e]], 1);
}

__global__ void k_scan1() {
  __shared__ int lds[256];
  int n = blockIdx.x * 256 + threadIdx.x;
  int deg = (n < N_NODESC) ? (g_cnt[n * 4] + g_cnt[n * 4 + 1] + g_cnt[n * 4 + 2]) : 0;
  lds[threadIdx.x] = deg;
  __syncthreads();
  for (int o = 128; o > 0; o >>= 1) {
    if (threadIdx.x < o) lds[threadIdx.x] += lds[threadIdx.x + o];
    __syncthreads();
  }
  if (threadIdx.x == 0) g_bsum[blockIdx.x] = lds[0];
}

__global__ void k_scan2() {
  __shared__ int lds[256];
  int t = threadIdx.x;
  int v = (t < 196) ? g_bsum[t] : 0;
  lds[t] = v;
  __syncthreads();
  for (int o = 1; o < 256; o <<= 1) {
    int u = (t >= o) ? lds[t - o] : 0;
    __syncthreads();
    lds[t] += u;
    __syncthreads();
  }
  if (t < 196) g_boff[t] = lds[t] - v;   // exclusive
}

__global__ void k_scan3() {
  __shared__ int lds[256];
  int n = blockIdx.x * 256 + threadIdx.x;
  int t = threadIdx.x;
  int deg = (n < N_NODESC) ? (g_cnt[n * 4] + g_cnt[n * 4 + 1] + g_cnt[n * 4 + 2]) : 0;
  lds[t] = deg;
  __syncthreads();
  for (int o = 1; o < 256; o <<= 1) {
    int u = (t >= o) ? lds[t - o] : 0;
    __syncthreads();
    lds[t] += u;
    __syncthreads();
  }
  if (n < N_NODESC) {
    int off = g_boff[blockIdx.x] + lds[t] - deg;
    g_rowoff[n] = off;
    g_cur[n] = off;
  }
  if (n == N_NODESC - 1) g_rowoff[N_NODESC] = g_boff[blockIdx.x] + lds[t];
}

__global__ void k_fill(const int* __restrict__ src, const int* __restrict__ dst,
                       const int* __restrict__ et) {
  int e = blockIdx.x * 256 + threadIdx.x;
  if (e >= N_EDGESC) return;
  int p = atomicAdd(&g_cur[dst[e]], 1);
  g_eidx[p] = (((unsigned)src[e]) << 2) | (unsigned)et[e];
}

__global__ void k_segoff(const int* __restrict__ seg) {
  int n = blockIdx.x * 256 + threadIdx.x;
  if (n >= N_NODESC) return;
  int g = seg[n];
  int gp = (n == 0) ? -1 : seg[n - 1];
  for (int t = gp + 1; t <= g; ++t) g_soff[t] = n;
  if (n == N_NODESC - 1)
    for (int t = g + 1; t <= NGRAPH; ++t) g_soff[t] = N_NODESC;
}

// ---------------- per-step kernels ----------------

#define ACC_ET(hv, et)                                                        \
  {                                                                           \
    float x0 = bf2f(hv[0]), x1 = bf2f(hv[1]), x2 = bf2f(hv[2]), x3 = bf2f(hv[3]); \
    if (et == 0)      { a0[0] += x0; a0[1] += x1; a0[2] += x2; a0[3] += x3; } \
    else if (et == 1) { a1[0] += x0; a1[1] += x1; a1[2] += x2; a1[3] += x3; } \
    else              { a2[0] += x0; a2[1] += x1; a2[2] += x2; a2[3] += x3; } \
  }

// p[n, e*256+d] = sum over in-edges of type e of h_bf16[src, d]; one wave per node.
// 8 independent gathers in flight (MLP-deepened; src is uniform-random over all
// nodes so placement tricks can't help — only latency depth can).
__global__ __launch_bounds__(256) void k_agg() {
  int node = blockIdx.x * 4 + (threadIdx.x >> 6);
  int lane = threadIdx.x & 63;
  if (node >= N_NODESC) return;
  float a0[4] = {0.f, 0.f, 0.f, 0.f};
  float a1[4] = {0.f, 0.f, 0.f, 0.f};
  float a2[4] = {0.f, 0.f, 0.f, 0.f};
  int s = g_rowoff[node], e = g_rowoff[node + 1];
  int i = s;
  for (; i + 8 <= e; i += 8) {
    unsigned v0 = g_eidx[i],     v1 = g_eidx[i + 1], v2 = g_eidx[i + 2], v3 = g_eidx[i + 3];
    unsigned v4 = g_eidx[i + 4], v5 = g_eidx[i + 5], v6 = g_eidx[i + 6], v7 = g_eidx[i + 7];
    u16x4 hv0 = *(const u16x4*)(g_ah + (size_t)(v0 >> 2) * 512 + 256 + lane * 4);
    u16x4 hv1 = *(const u16x4*)(g_ah + (size_t)(v1 >> 2) * 512 + 256 + lane * 4);
    u16x4 hv2 = *(const u16x4*)(g_ah + (size_t)(v2 >> 2) * 512 + 256 + lane * 4);
    u16x4 hv3 = *(const u16x4*)(g_ah + (size_t)(v3 >> 2) * 512 + 256 + lane * 4);
    u16x4 hv4 = *(const u16x4*)(g_ah + (size_t)(v4 >> 2) * 512 + 256 + lane * 4);
    u16x4 hv5 = *(const u16x4*)(g_ah + (size_t)(v5 >> 2) * 512 + 256 + lane * 4);
    u16x4 hv6 = *(const u16x4*)(g_ah + (size_t)(v6 >> 2) * 512 + 256 + lane * 4);
    u16x4 hv7 = *(const u16x4*)(g_ah + (size_t)(v7 >> 2) * 512 + 256 + lane * 4);
    int e0 = (int)(v0 & 3u), e1 = (int)(v1 & 3u), e2 = (int)(v2 & 3u), e3 = (int)(v3 & 3u);
    int e4 = (int)(v4 & 3u), e5 = (int)(v5 & 3u), e6 = (int)(v6 & 3u), e7 = (int)(v7 & 3u);
    ACC_ET(hv0, e0); ACC_ET(hv1, e1); ACC_ET(hv2, e2); ACC_ET(hv3, e3);
    ACC_ET(hv4, e4); ACC_ET(hv5, e5); ACC_ET(hv6, e6); ACC_ET(hv7, e7);
  }
  for (; i + 4 <= e; i += 4) {
    unsigned v0 = g_eidx[i], v1 = g_eidx[i + 1], v2 = g_eidx[i + 2], v3 = g_eidx[i + 3];
    u16x4 hv0 = *(const u16x4*)(g_ah + (size_t)(v0 >> 2) * 512 + 256 + lane * 4);
    u16x4 hv1 = *(const u16x4*)(g_ah + (size_t)(v1 >> 2) * 512 + 256 + lane * 4);
    u16x4 hv2 = *(const u16x4*)(g_ah + (size_t)(v2 >> 2) * 512 + 256 + lane * 4);
    u16x4 hv3 = *(const u16x4*)(g_ah + (size_t)(v3 >> 2) * 512 + 256 + lane * 4);
    int e0 = (int)(v0 & 3u), e1 = (int)(v1 & 3u), e2 = (int)(v2 & 3u), e3 = (int)(v3 & 3u);
    ACC_ET(hv0, e0); ACC_ET(hv1, e1); ACC_ET(hv2, e2); ACC_ET(hv3, e3);
  }
  for (; i < e; ++i) {
    unsigned v = g_eidx[i];
    u16x4 hv = *(const u16x4*)(g_ah + (size_t)(v >> 2) * 512 + 256 + lane * 4);
    int et = (int)(v & 3u);
    ACC_ET(hv, et);
  }
  size_t base = (size_t)node * DIM3 + lane * 4;
  u16x4 o0 = {f2bf(a0[0]), f2bf(a0[1]), f2bf(a0[2]), f2bf(a0[3])};
  u16x4 o1 = {f2bf(a1[0]), f2bf(a1[1]), f2bf(a1[2]), f2bf(a1[3])};
  u16x4 o2 = {f2bf(a2[0]), f2bf(a2[1]), f2bf(a2[2]), f2bf(a2[3])};
  *(u16x4*)(g_p + base)       = o0;
  *(u16x4*)(g_p + base + 256) = o1;
  *(u16x4*)(g_p + base + 512) = o2;
}

// a-part of g_ah = g_p @ g_Wc^T + cnt*b_msg  (R6-proven single-buffer body,
// XCD-banded BX=2 as HW-verified in R13).
__global__ __launch_bounds__(256) void k_gemm0(const float* __restrict__ bmsg) {
  constexpr int K = DIM3;
  __shared__ unsigned short lA[128 * 64];
  __shared__ unsigned short lB[128 * 64];
  const int tx = threadIdx.x;
  const int lane = tx & 63;
  const int wave = tx >> 6;
  const int wr = wave >> 1, wc = wave & 1;
  const int bid = blockIdx.x + blockIdx.y * 2;   // grid dim3(2, 392)
  const int xcd = bid & 7, ii = bid >> 3;        // ii in [0, 98)
  const int tileM = (xcd * 49 + (ii >> 1)) * 128;
  const int tileN = (ii & 1) * 128;

  f32x4 acc[4][4];
#pragma unroll
  for (int m = 0; m < 4; ++m)
#pragma unroll
    for (int n = 0; n < 4; ++n) {
      acc[m][n][0] = 0.f; acc[m][n][1] = 0.f; acc[m][n][2] = 0.f; acc[m][n][3] = 0.f;
    }

  const int f = lane & 15, q = lane >> 4, xr = f & 7;

  int srow[4], scg[4];
#pragma unroll
  for (int i = 0; i < 4; ++i) {
    int byteo = i * 4096 + tx * 16;
    srow[i] = byteo >> 7;
    scg[i] = ((byteo >> 4) & 7) ^ (srow[i] & 7);
  }

  for (int k0 = 0; k0 < K; k0 += 64) {
#pragma unroll
    for (int i = 0; i < 4; ++i) {
      int byteo = i * 4096 + tx * 16;
      async16((const void*)(g_p + (size_t)(tileM + srow[i]) * K + k0 + scg[i] * 8),
              (void*)((char*)lA + byteo));
      async16((const void*)(g_Wc + (size_t)(tileN + srow[i]) * K + k0 + scg[i] * 8),
              (void*)((char*)lB + byteo));
    }
    __syncthreads();
#pragma unroll
    for (int kk = 0; kk < 2; ++kk) {
      short8 af[4], bfr[4];
#pragma unroll
      for (int m = 0; m < 4; ++m)
        af[m] = *(const short8*)((const char*)lA +
                 (wr * 64 + m * 16 + f) * 128 + (((kk * 4 + q) ^ xr) * 16));
#pragma unroll
      for (int n = 0; n < 4; ++n)
        bfr[n] = *(const short8*)((const char*)lB +
                 (wc * 64 + n * 16 + f) * 128 + (((kk * 4 + q) ^ xr) * 16));
#pragma unroll
      for (int m = 0; m < 4; ++m)
#pragma unroll
        for (int n = 0; n < 4; ++n)
          acc[m][n] = __builtin_amdgcn_mfma_f32_16x16x32_bf16(af[m], bfr[n], acc[m][n], 0, 0, 0);
    }
    __syncthreads();
  }

#pragma unroll
  for (int m = 0; m < 4; ++m) {
    int row0 = tileM + wr * 64 + m * 16 + q * 4;
#pragma unroll
    for (int n = 0; n < 4; ++n) {
      int col = tileN + wc * 64 + n * 16 + f;
      f32x4 v = acc[m][n];
#pragma unroll
      for (int r = 0; r < 4; ++r) {
        int row = row0 + r;
        const int* c = g_cnt + (size_t)row * 4;
        float val = v[r] + c[0] * bmsg[col] + c[1] * bmsg[256 + col] + c[2] * bmsg[512 + col];
        g_ah[(size_t)row * 512 + col] = f2bf(val);
      }
    }
  }
}

// Shared gemmC body (R6/R13-proven staged+swizzled 128x128 tile).
template <int K, int BSTRIDE>
__device__ __forceinline__ void gemmC_body(unsigned short* lA, unsigned short* lB,
                                           const unsigned short* __restrict__ Bbase,
                                           int tileM, int brow0, int outcol0, int acol0) {
  const int tx = threadIdx.x;
  const int lane = tx & 63;
  const int wave = tx >> 6;
  const int wr = wave >> 1, wc = wave & 1;
  const int f = lane & 15, q = lane >> 4, xr = f & 7;

  f32x4 acc[4][4];
#pragma unroll
  for (int m = 0; m < 4; ++m)
#pragma unroll
    for (int n = 0; n < 4; ++n) {
      acc[m][n][0] = 0.f; acc[m][n][1] = 0.f; acc[m][n][2] = 0.f; acc[m][n][3] = 0.f;
    }

  int srow[4], scg[4];
#pragma unroll
  for (int i = 0; i < 4; ++i) {
    int byteo = i * 4096 + tx * 16;
    srow[i] = byteo >> 7;
    scg[i] = ((byteo >> 4) & 7) ^ (srow[i] & 7);
  }

  for (int k0 = 0; k0 < K; k0 += 64) {
#pragma unroll
    for (int i = 0; i < 4; ++i) {
      int byteo = i * 4096 + tx * 16;
      async16((const void*)(g_ah + (size_t)(tileM + srow[i]) * 512 + acol0 + k0 + scg[i] * 8),
              (void*)((char*)lA + byteo));
      async16((const void*)(Bbase + (size_t)(brow0 + srow[i]) * BSTRIDE + k0 + scg[i] * 8),
              (void*)((char*)lB + byteo));
    }
    __syncthreads();
#pragma unroll
    for (int kk = 0; kk < 2; ++kk) {
      short8 af[4], bfr[4];
#pragma unroll
      for (int m = 0; m < 4; ++m)
        af[m] = *(const short8*)((const char*)lA +
                 (wr * 64 + m * 16 + f) * 128 + (((kk * 4 + q) ^ xr) * 16));
#pragma unroll
      for (int n = 0; n < 4; ++n)
        bfr[n] = *(const short8*)((const char*)lB +
                 (wc * 64 + n * 16 + f) * 128 + (((kk * 4 + q) ^ xr) * 16));
#pragma unroll
      for (int m = 0; m < 4; ++m)
#pragma unroll
        for (int n = 0; n < 4; ++n)
          acc[m][n] = __builtin_amdgcn_mfma_f32_16x16x32_bf16(af[m], bfr[n], acc[m][n], 0, 0, 0);
    }
    __syncthreads();
  }

#pragma unroll
  for (int m = 0; m < 4; ++m) {
    int row0 = tileM + wr * 64 + m * 16 + q * 4;
#pragma unroll
    for (int n = 0; n < 4; ++n) {
      int col = outcol0 + wc * 64 + n * 16 + f;
      float bs = g_biasC[col];
#pragma unroll
      for (int r = 0; r < 4; ++r)
        g_gates[(size_t)(row0 + r) * 1024 + col] = (_Float16)(acc[m][n][r] + bs);
    }
  }
}

// Combined gate GEMM, heterogeneous K per col-tile region (R15-proven):
//  ct 0-3: rz (K=512 concat [a|h]);  ct 4-5: i_n (K=256, a-half);
//  ct 6-7: h_n (K=256, h-half). XCD-banded.
__global__ __launch_bounds__(256) void k_gemmC() {
  __shared__ unsigned short lA[128 * 64];
  __shared__ unsigned short lB[128 * 64];
  const int bid = blockIdx.x + blockIdx.y * 8;   // grid dim3(8, 392)
  const int xcd = bid & 7, ii = bid >> 3;        // ii in [0, 392)
  const int tileM = (xcd * 49 + (ii >> 3)) * 128;
  const int ct = ii & 7;
  if (ct < 4)
    gemmC_body<512, 512>(lA, lB, g_WC2, tileM, ct * 128, ct * 128, 0);
  else if (ct < 6)
    gemmC_body<256, 256>(lA, lB, g_WC2 + 262144, tileM, (ct - 4) * 128, ct * 128, 0);
  else
    gemmC_body<256, 256>(lA, lB, g_WC2 + 327680, tileM, (ct - 6) * 128, ct * 128, 256);
}

// GRU elementwise from combined gates. LAST=1 additionally computes the
// attention-gate logit per node (one 64-lane wave per node; shuffle-reduce).
template <int LAST>
__global__ void k_gru(const float* __restrict__ gw, const float* __restrict__ gb) {
  int i = blockIdx.x * 256 + threadIdx.x;   // N_NODESC*64
  int n = i >> 6, t = (i & 63) * 4;
  if (n >= N_NODESC) return;
  size_t bg = (size_t)n * 1024 + t;
  size_t b1 = (size_t)n * DIM + t;
  f16x4 rz_r = *(const f16x4*)(g_gates + bg);
  f16x4 rz_z = *(const f16x4*)(g_gates + bg + 256);
  f16x4 in4  = *(const f16x4*)(g_gates + bg + 512);
  f16x4 hn4  = *(const f16x4*)(g_gates + bg + 768);
  float4 h = *(const float4*)(g_hf + b1);
  float4 o;
#pragma unroll
  for (int j = 0; j < 4; ++j) {
    float r = sigm((float)rz_r[j]);
    float z = sigm((float)rz_z[j]);
    float nn = tanhf((float)in4[j] + r * (float)hn4[j]);
    float hj = (j == 0) ? h.x : (j == 1) ? h.y : (j == 2) ? h.z : h.w;
    float oj = (1.f - z) * nn + z * hj;
    if (j == 0) o.x = oj; else if (j == 1) o.y = oj; else if (j == 2) o.z = oj; else o.w = oj;
  }
  *(float4*)(g_hf + b1) = o;
  u16x4 ob = {f2bf(o.x), f2bf(o.y), f2bf(o.z), f2bf(o.w)};
  *(u16x4*)(g_ah + (size_t)n * 512 + 256 + t) = ob;
  if (LAST) {
    float4 w = *(const float4*)(gw + t);
    float p = o.x * w.x + o.y * w.y + o.z * w.z + o.w * w.w;
    for (int off = 32; off > 0; off >>= 1) p += __shfl_xor(p, off);
    if ((threadIdx.x & 63) == 0) g_gate[n] = p + gb[0];
  }
}

// ---------------- pooling ----------------

// Per-graph softmax max + denom (gate array is only 200 KB; 64 blocks).
__global__ void k_segred() {
  int g = blockIdx.x, t = threadIdx.x;
  __shared__ float red[256];
  int s = g_soff[g], e = g_soff[g + 1];
  float m = -3.4e38f;
  for (int n = s + t; n < e; n += 256) m = fmaxf(m, g_gate[n]);
  red[t] = m;
  __syncthreads();
  for (int o = 128; o > 0; o >>= 1) {
    if (t < o) red[t] = fmaxf(red[t], red[t + o]);
    __syncthreads();
  }
  m = red[0];
  __syncthreads();
  float sm = 0.f;
  for (int n = s + t; n < e; n += 256) sm += expf(g_gate[n] - m);
  red[t] = sm;
  __syncthreads();
  for (int o = 128; o > 0; o >>= 1) {
    if (t < o) red[t] += red[t + o];
    __syncthreads();
  }
  if (t == 0) {
    g_gmax[g] = m;
    g_gden[g] = (e > s && red[0] != 0.f) ? red[0] : 1.f;
  }
}

__global__ void k_zero_out(float* __restrict__ out) {
  out[blockIdx.x * 256 + threadIdx.x] = 0.f;   // 64*256 = NGRAPH*DIM
}

// 391 blocks x 128 nodes; thread t owns output dim t. seg_ids sorted ->
// accumulate and flush on graph boundary with one atomicAdd per (block,graph).
__global__ __launch_bounds__(256) void k_poolacc(const int* __restrict__ seg,
                                                 float* __restrict__ out) {
  __shared__ int   segL[128];
  __shared__ float alphaL[128];
  int base = blockIdx.x * 128;
  int t = threadIdx.x;
  if (t < 128) {
    int n = base + t;
    if (n < N_NODESC) {
      int g = seg[n];
      segL[t] = g;
      alphaL[t] = expf(g_gate[n] - g_gmax[g]) / g_gden[g];
    } else {
      segL[t] = -1;
    }
  }
  __syncthreads();
  float acc = 0.f;
  int gcur = segL[0];
  for (int j = 0; j < 128; ++j) {
    int gs = segL[j];
    if (gs < 0) break;
    if (gs != gcur) {
      atomicAdd(out + (size_t)gcur * DIM + t, acc);
      acc = 0.f;
      gcur = gs;
    }
    acc += alphaL[j] * g_hf[(size_t)(base + j) * DIM + t];
  }
  if (gcur >= 0) atomicAdd(out + (size_t)gcur * DIM + t, acc);
}

// ---------------- launch ----------------

extern "C" void kernel_launch(void* const* d_in, const int* in_sizes, int n_in,
                              void* d_out, int out_size, void* d_ws, size_t ws_size,
                              hipStream_t stream) {
  const int* x = (const int*)d_in[0];
  const int* src = (const int*)d_in[1];
  const int* dst = (const int*)d_in[2];
  const int* ety = (const int*)d_in[3];
  const int* seg = (const int*)d_in[4];
  const float* emb = (const float*)d_in[6];
  const float* Wmsg = (const float*)d_in[7];
  const float* bmsg = (const float*)d_in[8];
  const float* wih = (const float*)d_in[9];
  const float* whh = (const float*)d_in[10];
  const float* bih = (const float*)d_in[11];
  const float* bhh = (const float*)d_in[12];
  const float* gw = (const float*)d_in[13];
  const float* gb = (const float*)d_in[14];
  float* out = (float*)d_out;

  k_zero_cnt<<<NPAD2 * 4 / 256, 256, 0, stream>>>();
  k_prep_w<<<2308, 256, 0, stream>>>(Wmsg, wih, whh, bih, bhh);
  k_embed<<<12500, 256, 0, stream>>>(x, emb);
  k_count<<<(N_EDGESC + 255) / 256, 256, 0, stream>>>(dst, ety);
  k_scan1<<<196, 256, 0, stream>>>();
  k_scan2<<<1, 256, 0, stream>>>();
  k_scan3<<<196, 256, 0, stream>>>();
  k_fill<<<(N_EDGESC + 255) / 256, 256, 0, stream>>>(src, dst, ety);
  k_segoff<<<196, 256, 0, stream>>>(seg);

  for (int s = 0; s < NSTEPS; ++s) {
    k_agg<<<12500, 256, 0, stream>>>();
    k_gemm0<<<dim3(2, 392), 256, 0, stream>>>(bmsg);
    k_gemmC<<<dim3(8, 392), 256, 0, stream>>>();
    if (s < NSTEPS - 1)
      k_gru<0><<<12500, 256, 0, stream>>>(nullptr, nullptr);
    else
      k_gru<1><<<12500, 256, 0, stream>>>(gw, gb);
  }

  k_segred<<<NGRAPH, 256, 0, stream>>>();
  k_zero_out<<<NGRAPH, 256, 0, stream>>>(out);
  k_poolacc<<<391, 256, 0, stream>>>(seg, out);
}